// Round 4
// baseline (232.810 us; speedup 1.0000x reference)
//
#include <hip/hip_runtime.h>
#include <math.h>

// CBOW hierarchical-softmax loss — R4: batched epilogue transcendentals.
//   B=65536, C=10, D=18, E=128.
//   loss[b] = -sum_d log( p_d + 1e-9 ), p_d = (code==1) ? s_d : 1 - s_d,
//   s_d = sigmoid(u_d . v), v = mean_c in_embed[ctx[b,c]].
//
// R1 lesson: p computed literally as fp32 reference (s then 1-s, precise
// expf/logf/div) — near s==1, errors amplify by 1/(p+eps) up to ~1e9.
// R2 lesson: was VALU-bound; cut gathers/butterflies via half-wave split.
// R3 lesson: VALUBusy 51%, HBM 44% — latency-bound, ~310 VALU inst/wave of
// which ~180 were 9 redundant wave-wide transcendental passes (scalar work
// executed 64-wide). R4: place the 18 logits on 18 distinct lanes and do ONE
// transcendental pass + tree-sum.   (9 passes -> 1; -~160 inst/wave)
//
// Layout: one wave per example; lanes 0-31 = half 0 (even c/d), 32-63 =
// half 1 (odd). Rows read as 32 lanes x float4 = one coalesced 512B row per
// half per instruction.

constexpr int Bn = 65536;
constexpr int Cn = 10;
constexpr int Dn = 18;
constexpr float EPS = 1e-9f;

__global__ __launch_bounds__(256) void cbow_hs_kernel(
    const int* __restrict__ ctx,          // [B,C]
    const int* __restrict__ nodes,        // [B,D]
    const int* __restrict__ codes,        // [B,D]
    const float* __restrict__ in_embed,   // [V,E]
    const float* __restrict__ node_embed, // [N,E]
    float* __restrict__ out)              // [B]
{
    const int wave = threadIdx.x >> 6;   // 0..3
    const int lane = threadIdx.x & 63;
    const int sl   = lane & 31;          // sub-lane within half
    const bool hi  = lane >= 32;         // which half
    const int b = (blockIdx.x << 2) + wave;

    // ---- index preload (wave-uniform addresses), vectorized int2 ----
    int cidx[Cn];
    const int2* c2 = (const int2*)(ctx + b * Cn);
    #pragma unroll
    for (int k = 0; k < Cn / 2; ++k) {
        int2 t = c2[k]; cidx[2 * k] = t.x; cidx[2 * k + 1] = t.y;
    }
    int nidx[Dn];
    const int2* n2 = (const int2*)(nodes + b * Dn);
    #pragma unroll
    for (int k = 0; k < Dn / 2; ++k) {
        int2 t = n2[k]; nidx[2 * k] = t.x; nidx[2 * k + 1] = t.y;
    }

    const float4* __restrict__ in4 = (const float4*)in_embed;    // 32 f4/row
    const float4* __restrict__ ne4 = (const float4*)node_embed;

    // ---- v = mean of 10 context rows; halves take even/odd c ----
    float4 vs = make_float4(0.f, 0.f, 0.f, 0.f);
    #pragma unroll
    for (int c = 0; c < Cn; c += 2) {
        int idx = hi ? cidx[c + 1] : cidx[c];
        float4 e = in4[(size_t)idx * 32 + sl];
        vs.x += e.x; vs.y += e.y; vs.z += e.z; vs.w += e.w;
    }
    vs.x += __shfl_xor(vs.x, 32, 64);
    vs.y += __shfl_xor(vs.y, 32, 64);
    vs.z += __shfl_xor(vs.z, 32, 64);
    vs.w += __shfl_xor(vs.w, 32, 64);
    float4 v;
    v.x = vs.x * (1.0f / Cn); v.y = vs.y * (1.0f / Cn);
    v.z = vs.z * (1.0f / Cn); v.w = vs.w * (1.0f / Cn);

    // ---- 18 dots: half 0 -> even d, half 1 -> odd d (9 each) ----
    float pd[Dn / 2];
    #pragma unroll
    for (int i = 0; i < Dn / 2; ++i) {
        int idx = hi ? nidx[2 * i + 1] : nidx[2 * i];
        float4 u = ne4[(size_t)idx * 32 + sl];
        pd[i] = u.x * v.x + u.y * v.y + u.z * v.z + u.w * v.w;
    }

    // 5-level butterfly within each 32-lane half -> pd[i] replicated in half
    #pragma unroll
    for (int i = 0; i < Dn / 2; ++i) {
        #pragma unroll
        for (int m = 16; m >= 1; m >>= 1)
            pd[i] += __shfl_xor(pd[i], m, 64);
    }

    // ---- epilogue: ONE transcendental pass for all 18 (b,d) terms ----
    // Lane sl (sl<9) of half hi takes logit for d = 2*sl + hi.
    float myv = 0.f;
    #pragma unroll
    for (int i = 0; i < Dn / 2; ++i)
        myv = (sl == i) ? pd[i] : myv;

    const int d  = 2 * sl + (hi ? 1 : 0);
    const int cd = codes[b * Dn + ((sl < Dn / 2) ? d : 0)];  // L1-hot

    // Literal fp32 reference semantics (precise expf / IEEE div / logf):
    float s = 1.0f / (1.0f + expf(-myv));
    float p = (cd == 1) ? s : 1.0f - s;
    float t = (sl < Dn / 2) ? -logf(p + EPS) : 0.f;

    // tree-sum the 18 terms across the full wave
    #pragma unroll
    for (int m = 32; m >= 1; m >>= 1)
        t += __shfl_xor(t, m, 64);

    if (lane == 0) out[b] = t;
}

extern "C" void kernel_launch(void* const* d_in, const int* in_sizes, int n_in,
                              void* d_out, int out_size, void* d_ws, size_t ws_size,
                              hipStream_t stream) {
    const int*   ctx        = (const int*)d_in[0];
    const int*   path_nodes = (const int*)d_in[1];
    const int*   codes      = (const int*)d_in[2];
    const float* in_embed   = (const float*)d_in[3];
    const float* node_embed = (const float*)d_in[4];
    float*       out        = (float*)d_out;

    dim3 grid(Bn / 4);
    dim3 block(256);
    cbow_hs_kernel<<<grid, block, 0, stream>>>(ctx, path_nodes, codes,
                                               in_embed, node_embed, out);
}